// Round 4
// baseline (1601.714 us; speedup 1.0000x reference)
//
#include <hip/hip_runtime.h>
#include <hip/hip_bf16.h>
#include <math.h>

#define HID 128
#define NUM_G 20
#define EF 4
#define NN 20000
#define NE 640000
#define KN1 256           // node GEMM1 K

typedef __attribute__((ext_vector_type(8))) short short8;
typedef __attribute__((ext_vector_type(4))) short short4v;
typedef __attribute__((ext_vector_type(4))) float floatx4;
typedef __attribute__((ext_vector_type(4))) unsigned int uintx4;

__device__ __forceinline__ float silu_f(float v){
    return v * __builtin_amdgcn_rcpf(1.0f + __expf(-v));
}
__device__ __forceinline__ float sigm_f(float v){
    return __builtin_amdgcn_rcpf(1.0f + __expf(-v));
}
__device__ __forceinline__ float tanh_f(float v){
    return 1.0f - 2.0f * __builtin_amdgcn_rcpf(1.0f + __expf(2.0f * v));
}
__device__ __forceinline__ unsigned short f2bf(float v){
    unsigned int u = __float_as_uint(v);
    u = (u + 0x7fffu + ((u >> 16) & 1u)) >> 16;
    return (unsigned short)u;
}
__device__ __forceinline__ float bf2f(unsigned short u){
    return __uint_as_float(((unsigned int)u) << 16);
}
__device__ __forceinline__ unsigned int pk2(float a, float b){
    __hip_bfloat162 h = __float22bfloat162_rn(make_float2(a, b));
    return *(unsigned int*)&h;
}
__device__ __forceinline__ unsigned long long pk4(float a, float b, float c, float d){
    return (unsigned long long)pk2(a, b) | ((unsigned long long)pk2(c, d) << 32);
}
__device__ __forceinline__ float2 up2(unsigned int u){
    __hip_bfloat162 h = *(__hip_bfloat162*)&u;
    return __bfloat1622float2(h);
}

// ---- fused: weight transpose/bf16 (blocks 0..127) ∥ dst histogram (128..2127)
// ∥ agg/dxv zeroing (2128..4175, replaces a separate hipMemsetAsync dispatch) ----
__global__ __launch_bounds__(320) void prep_hist_kernel(
    const float* __restrict__ W_e1, const float* __restrict__ W_e2,
    const float* __restrict__ W_x1, const float* __restrict__ W_n1,
    const float* __restrict__ W_n2,
    unsigned short* __restrict__ WT1d, unsigned short* __restrict__ WT1s,
    unsigned short* __restrict__ WT1r,
    unsigned short* __restrict__ WT_e2, unsigned short* __restrict__ WT_x1,
    unsigned short* __restrict__ WT_n1, unsigned short* __restrict__ WT_n2,
    const int* __restrict__ edge_index, int* __restrict__ counts,
    float4* __restrict__ zero_base)
{
    int t = threadIdx.x;
    if (blockIdx.x < 128) {
        int n = blockIdx.x;
        if (t < HID) {
            WT1d[n*HID + t] = f2bf(W_e1[t*HID + n]);
            WT1s[n*HID + t] = f2bf(W_e1[(HID+t)*HID + n]);
            WT_e2[n*HID + t] = f2bf(W_e2[t*HID + n]);
            WT_x1[n*HID + t] = f2bf(W_x1[t*HID + n]);
            WT_n2[n*HID + t] = f2bf(W_n2[t*HID + n]);
        }
        if (t < 32) WT1r[n*32 + t] = (t < NUM_G+EF) ? f2bf(W_e1[(256+t)*HID + n]) : (unsigned short)0;
        if (t < KN1) WT_n1[n*KN1 + t] = f2bf(W_n1[t*HID + n]);
    } else if (blockIdx.x < 2128) {
        int e = (blockIdx.x - 128) * 320 + t;   // NE = 2000*320
        atomicAdd(&counts[edge_index[NE + e]], 1);
    } else {
        // zero agg (NN*HID floats) + dxv (NN*3 floats), contiguous = 655000 float4
        int idx = (blockIdx.x - 2128) * 320 + t;
        if (idx < (NN*HID + NN*3)/4) zero_base[idx] = make_float4(0.f,0.f,0.f,0.f);
    }
}

__global__ __launch_bounds__(1024) void scan_kernel(
    const int* __restrict__ counts, int* __restrict__ cursor)
{
    __shared__ int part[1024];
    const int t = threadIdx.x;
    const int CH = (NN + 1023) / 1024;   // 20
    int base = t * CH;
    int s = 0;
    for (int i = 0; i < CH; ++i) { int idx = base + i; if (idx < NN) s += counts[idx]; }
    part[t] = s; __syncthreads();
    for (int off = 1; off < 1024; off <<= 1) {
        int v = (t >= off) ? part[t - off] : 0;
        __syncthreads();
        part[t] += v;
        __syncthreads();
    }
    int run = (t == 0) ? 0 : part[t - 1];
    for (int i = 0; i < CH; ++i) {
        int idx = base + i;
        if (idx < NN) { cursor[idx] = run; run += counts[idx]; }
    }
}

// ---- Kernel C: pd (blocks 0..312, 4 waves x 16 nodes) ∥ build (blocks 313+) ----
// build writes ONE fused 32B edge record {s,d,rx,ry,rz,r,attr[4]bf16}.
#define PD_BLOCKS ((NN + 63) / 64)    // 313
__global__ __launch_bounds__(256) void build_pd_kernel(
    const int* __restrict__ edge_index, const float* __restrict__ x,
    const float* __restrict__ edge_attr, int* __restrict__ cursor,
    uintx4* __restrict__ rec,
    const float* __restrict__ h, const float* __restrict__ b_e1,
    const unsigned short* __restrict__ WT1d, const unsigned short* __restrict__ WT1s,
    unsigned short* __restrict__ PD, unsigned short* __restrict__ PS)
{
    if (blockIdx.x >= PD_BLOCKS) {
        // ---- build part ----
        int e = (blockIdx.x - PD_BLOCKS) * 256 + threadIdx.x;
        int s = edge_index[e];
        int d = edge_index[NE + e];
        int pos = atomicAdd(&cursor[d], 1);
        float rx = x[d*3+0] - x[s*3+0];
        float ry = x[d*3+1] - x[s*3+1];
        float rz = x[d*3+2] - x[s*3+2];
        float r  = sqrtf(rx*rx + ry*ry + rz*rz + 1e-8f);
        uintx4 lo, hi;
        lo[0] = (unsigned int)s; lo[1] = (unsigned int)d;
        lo[2] = __float_as_uint(rx); lo[3] = __float_as_uint(ry);
        hi[0] = __float_as_uint(rz); hi[1] = __float_as_uint(r);
        hi[2] = (unsigned int)f2bf(edge_attr[(size_t)e*EF + 0])
              | ((unsigned int)f2bf(edge_attr[(size_t)e*EF + 1]) << 16);
        hi[3] = (unsigned int)f2bf(edge_attr[(size_t)e*EF + 2])
              | ((unsigned int)f2bf(edge_attr[(size_t)e*EF + 3]) << 16);
        rec[(size_t)pos*2]     = lo;
        rec[(size_t)pos*2 + 1] = hi;
        return;
    }

    // ---- pd part: 4 autonomous waves, 16 nodes each; swapped mfma, b_e1 folded ----
    const int wv   = threadIdx.x >> 6;
    const int lane = threadIdx.x & 63;
    const int quad = lane >> 4;
    const int l15  = lane & 15;
    int node = blockIdx.x * 64 + wv * 16 + l15;
    if (node >= NN) node = NN - 1;     // duplicate-write guard (same data)

    short8 ah[4];
    #pragma unroll
    for (int kc = 0; kc < 4; ++kc) {
        const float* p = h + (size_t)node*HID + kc*32 + quad*8;
        float4 f0 = *(const float4*)(p);
        float4 f1 = *(const float4*)(p + 4);
        uintx4 u;
        u[0] = pk2(f0.x, f0.y); u[1] = pk2(f0.z, f0.w);
        u[2] = pk2(f1.x, f1.y); u[3] = pk2(f1.z, f1.w);
        ah[kc] = __builtin_bit_cast(short8, u);
    }

    floatx4 ad[8], as8[8];
    #pragma unroll
    for (int t = 0; t < 8; ++t) {
        float4 bb = *(const float4*)(b_e1 + t*16 + quad*4);
        ad[t]  = (floatx4){bb.x, bb.y, bb.z, bb.w};   // bias folded in
        as8[t] = (floatx4){0.f, 0.f, 0.f, 0.f};
    }
    #pragma unroll
    for (int kc = 0; kc < 4; ++kc) {
        #pragma unroll
        for (int t = 0; t < 8; ++t) {
            short8 bd = *(const short8*)(WT1d + (size_t)(t*16+l15)*HID + kc*32 + quad*8);
            short8 bs = *(const short8*)(WT1s + (size_t)(t*16+l15)*HID + kc*32 + quad*8);
            ad[t]  = __builtin_amdgcn_mfma_f32_16x16x32_bf16(bd, ah[kc], ad[t], 0, 0, 0);
            as8[t] = __builtin_amdgcn_mfma_f32_16x16x32_bf16(bs, ah[kc], as8[t], 0, 0, 0);
        }
    }
    #pragma unroll
    for (int t = 0; t < 8; ++t) {
        *(unsigned long long*)(PD + (size_t)node*HID + t*16 + quad*4) =
            pk4(ad[t][0], ad[t][1], ad[t][2], ad[t][3]);
        *(unsigned long long*)(PS + (size_t)node*HID + t*16 + quad*4) =
            pk4(as8[t][0], as8[t][1], as8[t][2], as8[t][3]);
    }
}

// ---- edge kernel: 128 threads = 2 autonomous waves, 32 sorted edges/wave.
// SWAPPED mfma: D[feat][edge]. ROUND 4: sequential 16-edge tiles in a
// #pragma unroll 1 loop. Each iteration OWNS its PD/PS gathers (born at tile
// start, dead at finalize) -> no gather regs live across MFMA clusters
// (rounds 2/3 spill lesson). Peak unified regs ~115 -> target 16 waves/CU.
// Weight frags reload per tile (L1-hot). msg/dxv reduces after the loop.
__global__ __launch_bounds__(128, 3) void egnn_edge_mfma(
    const uintx4* __restrict__ rec,
    const unsigned short* __restrict__ PD, const unsigned short* __restrict__ PS,
    const unsigned short* __restrict__ WT1r,
    const unsigned short* __restrict__ WT_e2,
    const unsigned short* __restrict__ WT_x1,
    const float* __restrict__ b_e2,
    const float* __restrict__ W_g,  const float* __restrict__ b_g,
    const float* __restrict__ b_x1, const float* __restrict__ W_x2,
    float* __restrict__ agg, float* __restrict__ dxv)
{
    __shared__ __align__(16) unsigned short T[2][32*HID];  // per-wave 8KB: rbf then m2
    __shared__ float s_g[2][32];
    __shared__ float s_vec[2][96];

    const int wv   = threadIdx.x >> 6;
    const int lane = threadIdx.x & 63;
    const int quad = lane >> 4;
    const int l15  = lane & 15;
    const int bid  = (int)(blockIdx.x & 7) * 1250 + (int)(blockIdx.x >> 3);
    const int e0   = (bid * 2 + wv) * 32;

    char* Tb = (char*)&T[wv][0];
    const int rsw = (l15 & 7) << 4;     // row swizzle (same for rows l15, 16+l15)

    // --- coalesced meta from fused record (lanes 0..31 own one edge each) ---
    int   sreg = 0, dreg = 0;
    float rxr = 0.f, ryr = 0.f, rzr = 0.f, rreg = 0.f;
    unsigned int au01 = 0, au23 = 0;
    if (lane < 32) {
        uintx4 lo = rec[(size_t)(e0 + lane)*2];
        uintx4 hi = rec[(size_t)(e0 + lane)*2 + 1];
        sreg = (int)lo[0]; dreg = (int)lo[1];
        rxr = __uint_as_float(lo[2]); ryr = __uint_as_float(lo[3]);
        rzr = __uint_as_float(hi[0]); rreg = __uint_as_float(hi[1]);
        au01 = hi[2]; au23 = hi[3];
    }
    // wave-uniform segment-boundary bitmask
    int nxt = __shfl(dreg, lane + 1);
    const unsigned int bmask =
        (unsigned int)__ballot(lane < 32 && (lane == 31 || dreg != nxt));

    #pragma unroll 1
    for (int ti = 0; ti < 2; ++ti) {
        const int rb = ti << 4;                      // row base in T / edge window
        const int   nd   = __shfl(dreg, rb + l15);
        const int   ns   = __shfl(sreg, rb + l15);
        const float rr   = __shfl(rreg, rb + l15);
        const unsigned int at01 = __shfl(au01, rb + l15);
        const unsigned int at23 = __shfl(au23, rb + l15);

        // --- this tile's PD/PS gathers: issued first, dead at finalize ---
        short8 pdv[4], psv[4];
        #pragma unroll
        for (int kc = 0; kc < 4; ++kc) {
            pdv[kc] = *(const short8*)(PD + (size_t)nd*HID + kc*32 + quad*8);
            psv[kc] = *(const short8*)(PS + (size_t)ns*HID + kc*32 + quad*8);
        }

        // rbf fragment for this tile (hides under gather latency)
        short8 ar;
        {
            const float step  = 10.0f / 19.0f;
            const float coeff = -0.5f / (step*step);
            uintx4 u;
            #pragma unroll
            for (int jp = 0; jp < 4; ++jp) {
                float v[2];
                #pragma unroll
                for (int q = 0; q < 2; ++q) {
                    int col = quad*8 + jp*2 + q;
                    float val = 0.f;
                    if (col < NUM_G) {
                        float d = rr - step*(float)col;
                        val = __expf(coeff*d*d);
                    } else if (col < NUM_G+EF) {
                        unsigned int w = (col < 22) ? at01 : at23;
                        val = bf2f((unsigned short)((col & 1) ? (w >> 16) : (w & 0xffffu)));
                    }
                    v[q] = val;
                }
                u[jp] = pk2(v[0], v[1]);
            }
            ar = __builtin_bit_cast(short8, u);
        }

        // --- GEMM1 (rbf), swapped: D[feat][edge] ---
        floatx4 acc[8];
        #pragma unroll
        for (int t = 0; t < 8; ++t) acc[t] = (floatx4){0,0,0,0};
        #pragma unroll
        for (int t = 0; t < 8; ++t) {
            short8 b = *(const short8*)(WT1r + (size_t)(t*16+l15)*32 + quad*8);
            acc[t] = __builtin_amdgcn_mfma_f32_16x16x32_bf16(b, ar, acc[t], 0, 0, 0);
        }
        #pragma unroll
        for (int t = 0; t < 8; ++t) {
            int bc = (t*16 + quad*4) * 2;
            *(unsigned long long*)(Tb + (rb + l15)*256 + (bc ^ rsw)) =
                pk4(acc[t][0], acc[t][1], acc[t][2], acc[t][3]);
        }
        __builtin_amdgcn_wave_barrier();

        // --- finalize: m1 = silu(PD[dst]+PS[src]+rbf); pdv/psv DIE here ---
        short8 a2[4];
        #pragma unroll
        for (int kc = 0; kc < 4; ++kc) {
            int bc = (kc*32 + quad*8) * 2;
            uintx4 rv = __builtin_bit_cast(uintx4, *(const short8*)(Tb + (rb + l15)*256 + (bc ^ rsw)));
            uintx4 pu = __builtin_bit_cast(uintx4, pdv[kc]);
            uintx4 su = __builtin_bit_cast(uintx4, psv[kc]);
            uintx4 o;
            #pragma unroll
            for (int w = 0; w < 4; ++w) {
                float2 p0 = up2(pu[w]), s0 = up2(su[w]), r0 = up2(rv[w]);
                o[w] = pk2(silu_f(p0.x + s0.x + r0.x), silu_f(p0.y + s0.y + r0.y));
            }
            a2[kc] = __builtin_bit_cast(short8, o);
        }

        // --- GEMM2 swapped: m2 = silu(m1 @ W_e2 + b); bias in C-init ---
        #pragma unroll
        for (int t = 0; t < 8; ++t) {
            float4 bb = *(const float4*)(b_e2 + t*16 + quad*4);
            acc[t] = (floatx4){bb.x, bb.y, bb.z, bb.w};
        }
        __builtin_amdgcn_s_setprio(1);
        #pragma unroll
        for (int kc = 0; kc < 4; ++kc) {
            #pragma unroll
            for (int t = 0; t < 8; ++t) {
                short8 b = *(const short8*)(WT_e2 + (size_t)(t*16+l15)*HID + kc*32 + quad*8);
                acc[t] = __builtin_amdgcn_mfma_f32_16x16x32_bf16(b, a2[kc], acc[t], 0, 0, 0);
            }
        }
        __builtin_amdgcn_s_setprio(0);

        // epilogue: silu, gate partial, stage m2 to T rows rb..rb+15
        {
            float gp = 0.f;
            #pragma unroll
            for (int t = 0; t < 8; ++t) {
                float4 wg = *(const float4*)(W_g + t*16 + quad*4);
                float m0 = silu_f(acc[t][0]), m1 = silu_f(acc[t][1]);
                float m2v = silu_f(acc[t][2]), m3 = silu_f(acc[t][3]);
                gp += m0*wg.x + m1*wg.y + m2v*wg.z + m3*wg.w;
                int bc = (t*16 + quad*4) * 2;
                *(unsigned long long*)(Tb + (rb + l15)*256 + (bc ^ rsw)) = pk4(m0, m1, m2v, m3);
            }
            gp += __shfl_xor(gp, 16); gp += __shfl_xor(gp, 32);
            if (lane < 16) s_g[wv][rb + l15] = sigm_f(gp + b_g[0]);
        }
        __builtin_amdgcn_wave_barrier();

        // --- GEMM3 swapped: coord head; bias b_x1 in C-init ---
        #pragma unroll
        for (int t = 0; t < 8; ++t) {
            float4 bb = *(const float4*)(b_x1 + t*16 + quad*4);
            acc[t] = (floatx4){bb.x, bb.y, bb.z, bb.w};
        }
        __builtin_amdgcn_s_setprio(1);
        #pragma unroll
        for (int kc = 0; kc < 4; ++kc) {
            int bc = (kc*32 + quad*8) * 2;
            short8 a3 = *(const short8*)(Tb + (rb + l15)*256 + (bc ^ rsw));
            #pragma unroll
            for (int t = 0; t < 8; ++t) {
                short8 b = *(const short8*)(WT_x1 + (size_t)(t*16+l15)*HID + kc*32 + quad*8);
                acc[t] = __builtin_amdgcn_mfma_f32_16x16x32_bf16(b, a3, acc[t], 0, 0, 0);
            }
        }
        __builtin_amdgcn_s_setprio(0);

        // coord head epilogue for this tile
        {
            float cp = 0.f;
            #pragma unroll
            for (int t = 0; t < 8; ++t) {
                float4 wx = *(const float4*)(W_x2 + t*16 + quad*4);
                cp += silu_f(acc[t][0])*wx.x + silu_f(acc[t][1])*wx.y
                    + silu_f(acc[t][2])*wx.z + silu_f(acc[t][3])*wx.w;
            }
            cp += __shfl_xor(cp, 16); cp += __shfl_xor(cp, 32);
            if (quad == 0) {                         // lanes 0..15 own edge rb+l15
                int el = rb + l15;
                float co = tanh_f(cp);
                float rx = __shfl(rxr, el), ry = __shfl(ryr, el), rz = __shfl(rzr, el);
                float rv = __shfl(rreg, el);
                float sc = __builtin_amdgcn_rcpf(rv + 1.0f) * co;
                s_vec[wv][el*3 + 0] = rx * sc;
                s_vec[wv][el*3 + 1] = ry * sc;
                s_vec[wv][el*3 + 2] = rz * sc;
            }
        }
    }
    __builtin_amdgcn_wave_barrier();

    // --- msg segmented reduce over all 32 rows (both tiles' m2 in T) ---
    {
        float am0 = 0.f, am1 = 0.f;
        #pragma unroll
        for (int r = 0; r < 32; ++r) {
            unsigned int pv = *(const unsigned int*)(Tb + r*256 + ((lane*4) ^ ((r&7)<<4)));
            float gr = s_g[wv][r];
            float2 f = up2(pv);
            am0 += f.x * gr;
            am1 += f.y * gr;
            if (bmask & (1u << r)) {
                int dr = __shfl(dreg, r);
                atomicAdd(&agg[(size_t)dr*HID + lane*2],     am0);
                atomicAdd(&agg[(size_t)dr*HID + lane*2 + 1], am1);
                am0 = 0.f; am1 = 0.f;
            }
        }
    }

    {
        float a = 0.f;
        #pragma unroll
        for (int r = 0; r < 32; ++r) {
            float vv = (lane < 3) ? s_vec[wv][r*3 + lane] : 0.f;
            a += vv;
            if (bmask & (1u << r)) {
                int dr = __shfl(dreg, r);       // uniform branch: all lanes execute
                if (lane < 3) atomicAdd(&dxv[(size_t)dr*3 + lane], a);
                a = 0.f;
            }
        }
    }
}

// ---- node kernel: ONE WAVE per block, 16 nodes, swapped mfma ----
// GEMM2 C-init = h + b_n2 (residual folded); stores are 8x float4.
__global__ __launch_bounds__(64, 4) void egnn_node_mfma(
    const float* __restrict__ h, const float* __restrict__ x,
    const int* __restrict__ mask,
    const float* __restrict__ agg, const float* __restrict__ dxv,
    const unsigned short* __restrict__ WT_n1, const float* __restrict__ b_n1,
    const unsigned short* __restrict__ WT_n2, const float* __restrict__ b_n2,
    float* __restrict__ h_out, float* __restrict__ x_out)
{
    __shared__ __align__(16) unsigned short T[16*HID];

    const int lane = threadIdx.x;
    const int quad = lane >> 4;
    const int l15  = lane & 15;
    const int n0   = blockIdx.x * 16;
    char* Tb = (char*)T;
    const int rsw = (l15 & 7) << 4;

    if (lane < 48) {
        int r = lane / 3, c = lane % 3;
        int n = n0 + r;
        x_out[n*3 + c] = x[n*3 + c] + dxv[n*3 + c] * (float)mask[n];
    }

    const int node = n0 + l15;
    short8 a1[8];
    #pragma unroll
    for (int kc = 0; kc < 4; ++kc) {
        const float* p = agg + (size_t)node*HID + kc*32 + quad*8;
        float4 f0 = *(const float4*)(p);
        float4 f1 = *(const float4*)(p + 4);
        uintx4 u;
        u[0] = pk2(f0.x, f0.y); u[1] = pk2(f0.z, f0.w);
        u[2] = pk2(f1.x, f1.y); u[3] = pk2(f1.z, f1.w);
        a1[kc] = __builtin_bit_cast(short8, u);
    }
    #pragma unroll
    for (int kc = 0; kc < 4; ++kc) {
        const float* p = h + (size_t)node*HID + kc*32 + quad*8;
        float4 f0 = *(const float4*)(p);
        float4 f1 = *(const float4*)(p + 4);
        uintx4 u;
        u[0] = pk2(f0.x, f0.y); u[1] = pk2(f0.z, f0.w);
        u[2] = pk2(f1.x, f1.y); u[3] = pk2(f1.z, f1.w);
        a1[4+kc] = __builtin_bit_cast(short8, u);
    }

    floatx4 acc[8];
    #pragma unroll
    for (int t = 0; t < 8; ++t) {
        float4 bb = *(const float4*)(b_n1 + t*16 + quad*4);
        acc[t] = (floatx4){bb.x, bb.y, bb.z, bb.w};
    }
    #pragma unroll
    for (int kc = 0; kc < 8; ++kc) {
        #pragma unroll
        for (int t = 0; t < 8; ++t) {
            short8 b = *(const short8*)(WT_n1 + (size_t)(t*16+l15)*KN1 + kc*32 + quad*8);
            acc[t] = __builtin_amdgcn_mfma_f32_16x16x32_bf16(b, a1[kc], acc[t], 0, 0, 0);
        }
    }
    #pragma unroll
    for (int t = 0; t < 8; ++t) {
        int bc = (t*16 + quad*4) * 2;
        *(unsigned long long*)(Tb + l15*256 + (bc ^ rsw)) =
            pk4(silu_f(acc[t][0]), silu_f(acc[t][1]), silu_f(acc[t][2]), silu_f(acc[t][3]));
    }
    __builtin_amdgcn_wave_barrier();

    short8 a2[4];
    #pragma unroll
    for (int kc = 0; kc < 4; ++kc) {
        int bc = (kc*32 + quad*8) * 2;
        a2[kc] = *(const short8*)(Tb + l15*256 + (bc ^ rsw));
    }
    #pragma unroll
    for (int t = 0; t < 8; ++t) {
        float4 hv = *(const float4*)(h + (size_t)node*HID + t*16 + quad*4);
        float4 bb = *(const float4*)(b_n2 + t*16 + quad*4);
        acc[t] = (floatx4){hv.x + bb.x, hv.y + bb.y, hv.z + bb.z, hv.w + bb.w};
    }
    #pragma unroll
    for (int kc = 0; kc < 4; ++kc) {
        #pragma unroll
        for (int t = 0; t < 8; ++t) {
            short8 b = *(const short8*)(WT_n2 + (size_t)(t*16+l15)*HID + kc*32 + quad*8);
            acc[t] = __builtin_amdgcn_mfma_f32_16x16x32_bf16(b, a2[kc], acc[t], 0, 0, 0);
        }
    }
    #pragma unroll
    for (int t = 0; t < 8; ++t) {
        *(floatx4*)(h_out + (size_t)node*HID + t*16 + quad*4) = acc[t];
    }
}

extern "C" void kernel_launch(void* const* d_in, const int* in_sizes, int n_in,
                              void* d_out, int out_size, void* d_ws, size_t ws_size,
                              hipStream_t stream) {
    const float* h          = (const float*)d_in[0];
    const float* x          = (const float*)d_in[1];
    const float* edge_attr  = (const float*)d_in[2];
    const int*   edge_index = (const int*)  d_in[3];
    const int*   mask       = (const int*)  d_in[4];
    const float* W_e1 = (const float*)d_in[5];
    const float* b_e1 = (const float*)d_in[6];
    const float* W_e2 = (const float*)d_in[7];
    const float* b_e2 = (const float*)d_in[8];
    const float* W_g  = (const float*)d_in[9];
    const float* b_g  = (const float*)d_in[10];
    const float* W_n1 = (const float*)d_in[11];
    const float* b_n1 = (const float*)d_in[12];
    const float* W_n2 = (const float*)d_in[13];
    const float* b_n2 = (const float*)d_in[14];
    const float* W_x1 = (const float*)d_in[15];
    const float* b_x1 = (const float*)d_in[16];
    const float* W_x2 = (const float*)d_in[17];

    char* ws = (char*)d_ws;
    float* agg = (float*)ws;                       ws += (size_t)NN*HID*4;
    float* dxv = (float*)ws;                       ws += (size_t)NN*3*4;
    int*   counts = (int*)ws;                      ws += (size_t)NN*4;
    int*   cursor = (int*)ws;                      ws += (size_t)NN*4;
    uintx4* rec   = (uintx4*)ws;                   ws += (size_t)NE*32;
    unsigned short* PD    = (unsigned short*)ws;   ws += (size_t)NN*HID*2;
    unsigned short* PS    = (unsigned short*)ws;   ws += (size_t)NN*HID*2;
    unsigned short* WT1d  = (unsigned short*)ws;   ws += (size_t)HID*HID*2;
    unsigned short* WT1s  = (unsigned short*)ws;   ws += (size_t)HID*HID*2;
    unsigned short* WT1r  = (unsigned short*)ws;   ws += (size_t)HID*32*2;
    unsigned short* WT_e2 = (unsigned short*)ws;   ws += (size_t)HID*HID*2;
    unsigned short* WT_x1 = (unsigned short*)ws;   ws += (size_t)HID*HID*2;
    unsigned short* WT_n1 = (unsigned short*)ws;   ws += (size_t)HID*KN1*2;
    unsigned short* WT_n2 = (unsigned short*)ws;   ws += (size_t)HID*HID*2;

    hipMemsetAsync(counts, 0, (size_t)NN*sizeof(int), stream);

    // agg+dxv zeroing folded into prep grid: (NN*HID + NN*3)/4 = 655000 float4
    // -> ceil(655000/320) = 2048 zero blocks
    prep_hist_kernel<<<128 + NE/320 + 2048, 320, 0, stream>>>(
        W_e1, W_e2, W_x1, W_n1, W_n2,
        WT1d, WT1s, WT1r, WT_e2, WT_x1, WT_n1, WT_n2,
        edge_index, counts, (float4*)agg);

    scan_kernel<<<1, 1024, 0, stream>>>(counts, cursor);

    build_pd_kernel<<<PD_BLOCKS + NE/256, 256, 0, stream>>>(
        edge_index, x, edge_attr, cursor, rec,
        h, b_e1, WT1d, WT1s, PD, PS);

    egnn_edge_mfma<<<NE/64, 128, 0, stream>>>(
        rec, PD, PS, WT1r, WT_e2, WT_x1,
        b_e2, W_g, b_g, b_x1, W_x2, agg, dxv);

    float* h_out = (float*)d_out;
    float* x_out = h_out + (size_t)NN*HID;

    egnn_node_mfma<<<NN/16, 64, 0, stream>>>(
        h, x, mask, agg, dxv, WT_n1, b_n1, WT_n2, b_n2, h_out, x_out);
}

// Round 5
// 445.104 us; speedup vs baseline: 3.5985x; 3.5985x over previous
//
#include <hip/hip_runtime.h>
#include <hip/hip_bf16.h>
#include <math.h>

#define HID 128
#define NUM_G 20
#define EF 4
#define NN 20000
#define NE 640000
#define KN1 256           // node GEMM1 K

typedef __attribute__((ext_vector_type(8))) short short8;
typedef __attribute__((ext_vector_type(4))) short short4v;
typedef __attribute__((ext_vector_type(4))) float floatx4;
typedef __attribute__((ext_vector_type(4))) unsigned int uintx4;

__device__ __forceinline__ float silu_f(float v){
    return v * __builtin_amdgcn_rcpf(1.0f + __expf(-v));
}
__device__ __forceinline__ float sigm_f(float v){
    return __builtin_amdgcn_rcpf(1.0f + __expf(-v));
}
__device__ __forceinline__ float tanh_f(float v){
    return 1.0f - 2.0f * __builtin_amdgcn_rcpf(1.0f + __expf(2.0f * v));
}
__device__ __forceinline__ unsigned short f2bf(float v){
    unsigned int u = __float_as_uint(v);
    u = (u + 0x7fffu + ((u >> 16) & 1u)) >> 16;
    return (unsigned short)u;
}
__device__ __forceinline__ float bf2f(unsigned short u){
    return __uint_as_float(((unsigned int)u) << 16);
}
__device__ __forceinline__ unsigned int pk2(float a, float b){
    __hip_bfloat162 h = __float22bfloat162_rn(make_float2(a, b));
    return *(unsigned int*)&h;
}
__device__ __forceinline__ unsigned long long pk4(float a, float b, float c, float d){
    return (unsigned long long)pk2(a, b) | ((unsigned long long)pk2(c, d) << 32);
}
__device__ __forceinline__ float2 up2(unsigned int u){
    __hip_bfloat162 h = *(__hip_bfloat162*)&u;
    return __bfloat1622float2(h);
}

// ---- fused: weight transpose/bf16 (blocks 0..127) ∥ dst histogram (128..2127)
// ∥ agg/dxv zeroing (2128..4175, replaces a separate hipMemsetAsync dispatch) ----
__global__ __launch_bounds__(320) void prep_hist_kernel(
    const float* __restrict__ W_e1, const float* __restrict__ W_e2,
    const float* __restrict__ W_x1, const float* __restrict__ W_n1,
    const float* __restrict__ W_n2,
    unsigned short* __restrict__ WT1d, unsigned short* __restrict__ WT1s,
    unsigned short* __restrict__ WT1r,
    unsigned short* __restrict__ WT_e2, unsigned short* __restrict__ WT_x1,
    unsigned short* __restrict__ WT_n1, unsigned short* __restrict__ WT_n2,
    const int* __restrict__ edge_index, int* __restrict__ counts,
    float4* __restrict__ zero_base)
{
    int t = threadIdx.x;
    if (blockIdx.x < 128) {
        int n = blockIdx.x;
        if (t < HID) {
            WT1d[n*HID + t] = f2bf(W_e1[t*HID + n]);
            WT1s[n*HID + t] = f2bf(W_e1[(HID+t)*HID + n]);
            WT_e2[n*HID + t] = f2bf(W_e2[t*HID + n]);
            WT_x1[n*HID + t] = f2bf(W_x1[t*HID + n]);
            WT_n2[n*HID + t] = f2bf(W_n2[t*HID + n]);
        }
        if (t < 32) WT1r[n*32 + t] = (t < NUM_G+EF) ? f2bf(W_e1[(256+t)*HID + n]) : (unsigned short)0;
        if (t < KN1) WT_n1[n*KN1 + t] = f2bf(W_n1[t*HID + n]);
    } else if (blockIdx.x < 2128) {
        int e = (blockIdx.x - 128) * 320 + t;   // NE = 2000*320
        atomicAdd(&counts[edge_index[NE + e]], 1);
    } else {
        // zero agg (NN*HID floats) + dxv (NN*3 floats), contiguous = 655000 float4
        int idx = (blockIdx.x - 2128) * 320 + t;
        if (idx < (NN*HID + NN*3)/4) zero_base[idx] = make_float4(0.f,0.f,0.f,0.f);
    }
}

__global__ __launch_bounds__(1024) void scan_kernel(
    const int* __restrict__ counts, int* __restrict__ cursor)
{
    __shared__ int part[1024];
    const int t = threadIdx.x;
    const int CH = (NN + 1023) / 1024;   // 20
    int base = t * CH;
    int s = 0;
    for (int i = 0; i < CH; ++i) { int idx = base + i; if (idx < NN) s += counts[idx]; }
    part[t] = s; __syncthreads();
    for (int off = 1; off < 1024; off <<= 1) {
        int v = (t >= off) ? part[t - off] : 0;
        __syncthreads();
        part[t] += v;
        __syncthreads();
    }
    int run = (t == 0) ? 0 : part[t - 1];
    for (int i = 0; i < CH; ++i) {
        int idx = base + i;
        if (idx < NN) { cursor[idx] = run; run += counts[idx]; }
    }
}

// ---- Kernel C: pd (blocks 0..312, 4 waves x 16 nodes) ∥ build (blocks 313+) ----
// build writes ONE fused 32B edge record {s,d,rx,ry,rz,r,attr[4]bf16}.
#define PD_BLOCKS ((NN + 63) / 64)    // 313
__global__ __launch_bounds__(256) void build_pd_kernel(
    const int* __restrict__ edge_index, const float* __restrict__ x,
    const float* __restrict__ edge_attr, int* __restrict__ cursor,
    uintx4* __restrict__ rec,
    const float* __restrict__ h, const float* __restrict__ b_e1,
    const unsigned short* __restrict__ WT1d, const unsigned short* __restrict__ WT1s,
    unsigned short* __restrict__ PD, unsigned short* __restrict__ PS)
{
    if (blockIdx.x >= PD_BLOCKS) {
        // ---- build part ----
        int e = (blockIdx.x - PD_BLOCKS) * 256 + threadIdx.x;
        int s = edge_index[e];
        int d = edge_index[NE + e];
        int pos = atomicAdd(&cursor[d], 1);
        float rx = x[d*3+0] - x[s*3+0];
        float ry = x[d*3+1] - x[s*3+1];
        float rz = x[d*3+2] - x[s*3+2];
        float r  = sqrtf(rx*rx + ry*ry + rz*rz + 1e-8f);
        uintx4 lo, hi;
        lo[0] = (unsigned int)s; lo[1] = (unsigned int)d;
        lo[2] = __float_as_uint(rx); lo[3] = __float_as_uint(ry);
        hi[0] = __float_as_uint(rz); hi[1] = __float_as_uint(r);
        hi[2] = (unsigned int)f2bf(edge_attr[(size_t)e*EF + 0])
              | ((unsigned int)f2bf(edge_attr[(size_t)e*EF + 1]) << 16);
        hi[3] = (unsigned int)f2bf(edge_attr[(size_t)e*EF + 2])
              | ((unsigned int)f2bf(edge_attr[(size_t)e*EF + 3]) << 16);
        rec[(size_t)pos*2]     = lo;
        rec[(size_t)pos*2 + 1] = hi;
        return;
    }

    // ---- pd part: 4 autonomous waves, 16 nodes each; swapped mfma, b_e1 folded ----
    const int wv   = threadIdx.x >> 6;
    const int lane = threadIdx.x & 63;
    const int quad = lane >> 4;
    const int l15  = lane & 15;
    int node = blockIdx.x * 64 + wv * 16 + l15;
    if (node >= NN) node = NN - 1;     // duplicate-write guard (same data)

    short8 ah[4];
    #pragma unroll
    for (int kc = 0; kc < 4; ++kc) {
        const float* p = h + (size_t)node*HID + kc*32 + quad*8;
        float4 f0 = *(const float4*)(p);
        float4 f1 = *(const float4*)(p + 4);
        uintx4 u;
        u[0] = pk2(f0.x, f0.y); u[1] = pk2(f0.z, f0.w);
        u[2] = pk2(f1.x, f1.y); u[3] = pk2(f1.z, f1.w);
        ah[kc] = __builtin_bit_cast(short8, u);
    }

    floatx4 ad[8], as8[8];
    #pragma unroll
    for (int t = 0; t < 8; ++t) {
        float4 bb = *(const float4*)(b_e1 + t*16 + quad*4);
        ad[t]  = (floatx4){bb.x, bb.y, bb.z, bb.w};   // bias folded in
        as8[t] = (floatx4){0.f, 0.f, 0.f, 0.f};
    }
    #pragma unroll
    for (int kc = 0; kc < 4; ++kc) {
        #pragma unroll
        for (int t = 0; t < 8; ++t) {
            short8 bd = *(const short8*)(WT1d + (size_t)(t*16+l15)*HID + kc*32 + quad*8);
            short8 bs = *(const short8*)(WT1s + (size_t)(t*16+l15)*HID + kc*32 + quad*8);
            ad[t]  = __builtin_amdgcn_mfma_f32_16x16x32_bf16(bd, ah[kc], ad[t], 0, 0, 0);
            as8[t] = __builtin_amdgcn_mfma_f32_16x16x32_bf16(bs, ah[kc], as8[t], 0, 0, 0);
        }
    }
    #pragma unroll
    for (int t = 0; t < 8; ++t) {
        *(unsigned long long*)(PD + (size_t)node*HID + t*16 + quad*4) =
            pk4(ad[t][0], ad[t][1], ad[t][2], ad[t][3]);
        *(unsigned long long*)(PS + (size_t)node*HID + t*16 + quad*4) =
            pk4(as8[t][0], as8[t][1], as8[t][2], as8[t][3]);
    }
}

// ---- edge kernel: 128 threads = 2 autonomous waves, 32 sorted edges/wave.
// ROUND 5: REVERT to the round-1 spill-free schedule (243 us, hbm 9e7):
// all PD/PS gathers up front, two 16-edge tiles in PARALLEL, phases strictly
// serial. LESSON (r2/r3/r4, hbm 3.5e8->7.7e8->38.7e8): under (128,3) the
// allocator is pinned at 84 VGPR; ANY restructure that widens liveness
// (per-kc interleave, cross-tile prefetch, rolled tile loop) compiles to
// scratch spills, and dur tracks hbm_bytes. DO NOT: interleave finalize into
// MFMA loops; hold gathers across clusters; roll the tile loop.
// Only delta vs round-1: meta from fused 32B rec; attr via 4 shuffled words
// (die at rbf-build).
__global__ __launch_bounds__(128, 3) void egnn_edge_mfma(
    const uintx4* __restrict__ rec,
    const unsigned short* __restrict__ PD, const unsigned short* __restrict__ PS,
    const unsigned short* __restrict__ WT1r,
    const unsigned short* __restrict__ WT_e2,
    const unsigned short* __restrict__ WT_x1,
    const float* __restrict__ b_e2,
    const float* __restrict__ W_g,  const float* __restrict__ b_g,
    const float* __restrict__ b_x1, const float* __restrict__ W_x2,
    float* __restrict__ agg, float* __restrict__ dxv)
{
    __shared__ __align__(16) unsigned short T[2][32*HID];  // m1-pre, then m2 (swizzled)
    __shared__ float s_g[2][32];
    __shared__ float s_vec[2][96];

    const int wv   = threadIdx.x >> 6;
    const int lane = threadIdx.x & 63;
    const int quad = lane >> 4;
    const int l15  = lane & 15;
    const int bid  = (int)(blockIdx.x & 7) * 1250 + (int)(blockIdx.x >> 3);
    const int e0   = (bid * 2 + wv) * 32;

    char* Tb = (char*)&T[wv][0];
    const int rsw = (l15 & 7) << 4;     // row swizzle for rows l15 and 16+l15 (same)

    // --- coalesced meta from fused record (lanes 0..31 own one edge each) ---
    int   sreg = 0, dreg = 0;
    float rxr = 0.f, ryr = 0.f, rzr = 0.f, rreg = 0.f;
    unsigned int au01 = 0, au23 = 0;
    if (lane < 32) {
        uintx4 lo = rec[(size_t)(e0 + lane)*2];
        uintx4 hi = rec[(size_t)(e0 + lane)*2 + 1];
        sreg = (int)lo[0]; dreg = (int)lo[1];
        rxr = __uint_as_float(lo[2]); ryr = __uint_as_float(lo[3]);
        rzr = __uint_as_float(hi[0]); rreg = __uint_as_float(hi[1]);
        au01 = hi[2]; au23 = hi[3];
    }
    // wave-uniform segment-boundary bitmask
    int nxt = __shfl(dreg, lane + 1);
    const unsigned int bmask =
        (unsigned int)__ballot(lane < 32 && (lane == 31 || dreg != nxt));

    const int   nd0 = __shfl(dreg, l15);
    const int   ns0 = __shfl(sreg, l15);
    const float rr0 = __shfl(rreg, l15);
    const int   nd1 = __shfl(dreg, 16 + l15);
    const int   ns1 = __shfl(sreg, 16 + l15);
    const float rr1 = __shfl(rreg, 16 + l15);
    const unsigned int at01_0 = __shfl(au01, l15),      at23_0 = __shfl(au23, l15);
    const unsigned int at01_1 = __shfl(au01, 16 + l15), at23_1 = __shfl(au23, 16 + l15);

    // --- issue long-latency PD/PS gathers first (frag layout) ---
    short8 pdv0[4], psv0[4], pdv1[4], psv1[4];
    #pragma unroll
    for (int kc = 0; kc < 4; ++kc) {
        pdv0[kc] = *(const short8*)(PD + (size_t)nd0*HID + kc*32 + quad*8);
        psv0[kc] = *(const short8*)(PS + (size_t)ns0*HID + kc*32 + quad*8);
        pdv1[kc] = *(const short8*)(PD + (size_t)nd1*HID + kc*32 + quad*8);
        psv1[kc] = *(const short8*)(PS + (size_t)ns1*HID + kc*32 + quad*8);
    }

    // rbf fragments (attr from the shuffled record words; regs die here)
    short8 ar0, ar1;
    {
        const float step  = 10.0f / 19.0f;
        const float coeff = -0.5f / (step*step);
        uintx4 u0, u1;
        #pragma unroll
        for (int jp = 0; jp < 4; ++jp) {
            float v[4];
            #pragma unroll
            for (int half = 0; half < 2; ++half) {
                float rr = half ? rr1 : rr0;
                #pragma unroll
                for (int q = 0; q < 2; ++q) {
                    int col = quad*8 + jp*2 + q;
                    float val = 0.f;
                    if (col < NUM_G) {
                        float d = rr - step*(float)col;
                        val = __expf(coeff*d*d);
                    } else if (col < NUM_G+EF) {
                        unsigned int w = (col < 22) ? (half ? at01_1 : at01_0)
                                                    : (half ? at23_1 : at23_0);
                        val = bf2f((unsigned short)((col & 1) ? (w >> 16) : (w & 0xffffu)));
                    }
                    v[half*2 + q] = val;
                }
            }
            u0[jp] = pk2(v[0], v[1]);
            u1[jp] = pk2(v[2], v[3]);
        }
        ar0 = __builtin_bit_cast(short8, u0);
        ar1 = __builtin_bit_cast(short8, u1);
    }

    // --- GEMM1 (rbf), swapped: D[feat][edge] ---
    floatx4 acc0[8], acc1[8];
    #pragma unroll
    for (int t = 0; t < 8; ++t) { acc0[t] = (floatx4){0,0,0,0}; acc1[t] = (floatx4){0,0,0,0}; }
    #pragma unroll
    for (int t = 0; t < 8; ++t) {
        short8 b = *(const short8*)(WT1r + (size_t)(t*16+l15)*32 + quad*8);
        acc0[t] = __builtin_amdgcn_mfma_f32_16x16x32_bf16(b, ar0, acc0[t], 0, 0, 0);
        acc1[t] = __builtin_amdgcn_mfma_f32_16x16x32_bf16(b, ar1, acc1[t], 0, 0, 0);
    }
    // stage rbf pre-sum to T rows l15 (tile0) / 16+l15 (tile1): one b64 per tile
    #pragma unroll
    for (int t = 0; t < 8; ++t) {
        int bc = (t*16 + quad*4) * 2;
        *(unsigned long long*)(Tb + l15*256      + (bc ^ rsw)) =
            pk4(acc0[t][0], acc0[t][1], acc0[t][2], acc0[t][3]);
        *(unsigned long long*)(Tb + (16+l15)*256 + (bc ^ rsw)) =
            pk4(acc1[t][0], acc1[t][1], acc1[t][2], acc1[t][3]);
    }
    __builtin_amdgcn_wave_barrier();

    // layer-1 finalize: m1 = silu(PD[dst]+PS[src]+rbf)  (bias folded in PD)
    short8 a2[8];
    #pragma unroll
    for (int kc = 0; kc < 4; ++kc) {
        int bc = (kc*32 + quad*8) * 2;
        uintx4 rv0 = __builtin_bit_cast(uintx4, *(const short8*)(Tb + l15*256      + (bc ^ rsw)));
        uintx4 rv1 = __builtin_bit_cast(uintx4, *(const short8*)(Tb + (16+l15)*256 + (bc ^ rsw)));
        uintx4 pu0 = __builtin_bit_cast(uintx4, pdv0[kc]);
        uintx4 su0 = __builtin_bit_cast(uintx4, psv0[kc]);
        uintx4 pu1 = __builtin_bit_cast(uintx4, pdv1[kc]);
        uintx4 su1 = __builtin_bit_cast(uintx4, psv1[kc]);
        uintx4 o0, o1;
        #pragma unroll
        for (int w = 0; w < 4; ++w) {
            float2 p0 = up2(pu0[w]), s0 = up2(su0[w]), r0 = up2(rv0[w]);
            float2 p1 = up2(pu1[w]), s1 = up2(su1[w]), r1 = up2(rv1[w]);
            o0[w] = pk2(silu_f(p0.x + s0.x + r0.x), silu_f(p0.y + s0.y + r0.y));
            o1[w] = pk2(silu_f(p1.x + s1.x + r1.x), silu_f(p1.y + s1.y + r1.y));
        }
        a2[kc]   = __builtin_bit_cast(short8, o0);
        a2[4+kc] = __builtin_bit_cast(short8, o1);
    }
    __builtin_amdgcn_wave_barrier();

    // --- GEMM2 swapped: m2 = silu(m1 @ W_e2 + b); bias in C-init ---
    #pragma unroll
    for (int t = 0; t < 8; ++t) {
        float4 bb = *(const float4*)(b_e2 + t*16 + quad*4);
        acc0[t] = (floatx4){bb.x, bb.y, bb.z, bb.w};
        acc1[t] = acc0[t];
    }
    __builtin_amdgcn_s_setprio(1);
    #pragma unroll
    for (int kc = 0; kc < 4; ++kc) {
        #pragma unroll
        for (int t = 0; t < 8; ++t) {
            short8 b = *(const short8*)(WT_e2 + (size_t)(t*16+l15)*HID + kc*32 + quad*8);
            acc0[t] = __builtin_amdgcn_mfma_f32_16x16x32_bf16(b, a2[kc],   acc0[t], 0, 0, 0);
            acc1[t] = __builtin_amdgcn_mfma_f32_16x16x32_bf16(b, a2[4+kc], acc1[t], 0, 0, 0);
        }
    }
    __builtin_amdgcn_s_setprio(0);
    {
        float gp0 = 0.f, gp1 = 0.f;
        #pragma unroll
        for (int t = 0; t < 8; ++t) {
            float4 wg = *(const float4*)(W_g + t*16 + quad*4);
            float m0 = silu_f(acc0[t][0]), m1 = silu_f(acc0[t][1]);
            float m2v = silu_f(acc0[t][2]), m3 = silu_f(acc0[t][3]);
            float n0v = silu_f(acc1[t][0]), n1 = silu_f(acc1[t][1]);
            float n2 = silu_f(acc1[t][2]),  n3 = silu_f(acc1[t][3]);
            gp0 += m0*wg.x + m1*wg.y + m2v*wg.z + m3*wg.w;
            gp1 += n0v*wg.x + n1*wg.y + n2*wg.z + n3*wg.w;
            int bc = (t*16 + quad*4) * 2;
            *(unsigned long long*)(Tb + l15*256      + (bc ^ rsw)) = pk4(m0, m1, m2v, m3);
            *(unsigned long long*)(Tb + (16+l15)*256 + (bc ^ rsw)) = pk4(n0v, n1, n2, n3);
        }
        gp0 += __shfl_xor(gp0, 16); gp0 += __shfl_xor(gp0, 32);
        gp1 += __shfl_xor(gp1, 16); gp1 += __shfl_xor(gp1, 32);
        if (lane < 16) {
            const float bg0 = b_g[0];
            s_g[wv][l15]      = sigm_f(gp0 + bg0);
            s_g[wv][16 + l15] = sigm_f(gp1 + bg0);
        }
    }
    __builtin_amdgcn_wave_barrier();

    // --- GEMM3 swapped: coord head; bias b_x1 in C-init ---
    #pragma unroll
    for (int kc = 0; kc < 4; ++kc) {
        int bc = (kc*32 + quad*8) * 2;
        a2[kc]   = *(const short8*)(Tb + l15*256      + (bc ^ rsw));
        a2[4+kc] = *(const short8*)(Tb + (16+l15)*256 + (bc ^ rsw));
    }
    #pragma unroll
    for (int t = 0; t < 8; ++t) {
        float4 bb = *(const float4*)(b_x1 + t*16 + quad*4);
        acc0[t] = (floatx4){bb.x, bb.y, bb.z, bb.w};
        acc1[t] = acc0[t];
    }
    __builtin_amdgcn_s_setprio(1);
    #pragma unroll
    for (int kc = 0; kc < 4; ++kc) {
        #pragma unroll
        for (int t = 0; t < 8; ++t) {
            short8 b = *(const short8*)(WT_x1 + (size_t)(t*16+l15)*HID + kc*32 + quad*8);
            acc0[t] = __builtin_amdgcn_mfma_f32_16x16x32_bf16(b, a2[kc],   acc0[t], 0, 0, 0);
            acc1[t] = __builtin_amdgcn_mfma_f32_16x16x32_bf16(b, a2[4+kc], acc1[t], 0, 0, 0);
        }
    }
    __builtin_amdgcn_s_setprio(0);

    // --- msg segmented reduce + atomics NOW (drain overlaps GEMM3 epilogue) ---
    {
        float am0 = 0.f, am1 = 0.f;
        #pragma unroll
        for (int r = 0; r < 32; ++r) {
            unsigned int pv = *(const unsigned int*)(Tb + r*256 + ((lane*4) ^ ((r&7)<<4)));
            float gr = s_g[wv][r];
            float2 f = up2(pv);
            am0 += f.x * gr;
            am1 += f.y * gr;
            if (bmask & (1u << r)) {
                int dr = __shfl(dreg, r);
                atomicAdd(&agg[(size_t)dr*HID + lane*2],     am0);
                atomicAdd(&agg[(size_t)dr*HID + lane*2 + 1], am1);
                am0 = 0.f; am1 = 0.f;
            }
        }
    }

    {
        float cp0 = 0.f, cp1 = 0.f;
        #pragma unroll
        for (int t = 0; t < 8; ++t) {
            float4 wx = *(const float4*)(W_x2 + t*16 + quad*4);
            cp0 += silu_f(acc0[t][0])*wx.x + silu_f(acc0[t][1])*wx.y
                 + silu_f(acc0[t][2])*wx.z + silu_f(acc0[t][3])*wx.w;
            cp1 += silu_f(acc1[t][0])*wx.x + silu_f(acc1[t][1])*wx.y
                 + silu_f(acc1[t][2])*wx.z + silu_f(acc1[t][3])*wx.w;
        }
        cp0 += __shfl_xor(cp0, 16); cp0 += __shfl_xor(cp0, 32);
        cp1 += __shfl_xor(cp1, 16); cp1 += __shfl_xor(cp1, 32);
        if (quad < 2) {                         // active lanes 0..31 = shfl sources
            int el = quad*16 + l15;             // edge index in window
            float cp = (quad == 0) ? cp0 : cp1;
            float co = tanh_f(cp);
            float rx = __shfl(rxr, el), ry = __shfl(ryr, el), rz = __shfl(rzr, el);
            float rv = __shfl(rreg, el);
            float sc = __builtin_amdgcn_rcpf(rv + 1.0f) * co;
            s_vec[wv][el*3 + 0] = rx * sc;
            s_vec[wv][el*3 + 1] = ry * sc;
            s_vec[wv][el*3 + 2] = rz * sc;
        }
    }
    __builtin_amdgcn_wave_barrier();

    {
        float a = 0.f;
        #pragma unroll
        for (int r = 0; r < 32; ++r) {
            float vv = (lane < 3) ? s_vec[wv][r*3 + lane] : 0.f;
            a += vv;
            if (bmask & (1u << r)) {
                int dr = __shfl(dreg, r);       // uniform branch: all lanes execute
                if (lane < 3) atomicAdd(&dxv[(size_t)dr*3 + lane], a);
                a = 0.f;
            }
        }
    }
}

// ---- node kernel: ONE WAVE per block, 16 nodes, swapped mfma ----
// GEMM2 C-init = h + b_n2 (residual folded); stores are 8x float4.
__global__ __launch_bounds__(64, 4) void egnn_node_mfma(
    const float* __restrict__ h, const float* __restrict__ x,
    const int* __restrict__ mask,
    const float* __restrict__ agg, const float* __restrict__ dxv,
    const unsigned short* __restrict__ WT_n1, const float* __restrict__ b_n1,
    const unsigned short* __restrict__ WT_n2, const float* __restrict__ b_n2,
    float* __restrict__ h_out, float* __restrict__ x_out)
{
    __shared__ __align__(16) unsigned short T[16*HID];

    const int lane = threadIdx.x;
    const int quad = lane >> 4;
    const int l15  = lane & 15;
    const int n0   = blockIdx.x * 16;
    char* Tb = (char*)T;
    const int rsw = (l15 & 7) << 4;

    if (lane < 48) {
        int r = lane / 3, c = lane % 3;
        int n = n0 + r;
        x_out[n*3 + c] = x[n*3 + c] + dxv[n*3 + c] * (float)mask[n];
    }

    const int node = n0 + l15;
    short8 a1[8];
    #pragma unroll
    for (int kc = 0; kc < 4; ++kc) {
        const float* p = agg + (size_t)node*HID + kc*32 + quad*8;
        float4 f0 = *(const float4*)(p);
        float4 f1 = *(const float4*)(p + 4);
        uintx4 u;
        u[0] = pk2(f0.x, f0.y); u[1] = pk2(f0.z, f0.w);
        u[2] = pk2(f1.x, f1.y); u[3] = pk2(f1.z, f1.w);
        a1[kc] = __builtin_bit_cast(short8, u);
    }
    #pragma unroll
    for (int kc = 0; kc < 4; ++kc) {
        const float* p = h + (size_t)node*HID + kc*32 + quad*8;
        float4 f0 = *(const float4*)(p);
        float4 f1 = *(const float4*)(p + 4);
        uintx4 u;
        u[0] = pk2(f0.x, f0.y); u[1] = pk2(f0.z, f0.w);
        u[2] = pk2(f1.x, f1.y); u[3] = pk2(f1.z, f1.w);
        a1[4+kc] = __builtin_bit_cast(short8, u);
    }

    floatx4 acc[8];
    #pragma unroll
    for (int t = 0; t < 8; ++t) {
        float4 bb = *(const float4*)(b_n1 + t*16 + quad*4);
        acc[t] = (floatx4){bb.x, bb.y, bb.z, bb.w};
    }
    #pragma unroll
    for (int kc = 0; kc < 8; ++kc) {
        #pragma unroll
        for (int t = 0; t < 8; ++t) {
            short8 b = *(const short8*)(WT_n1 + (size_t)(t*16+l15)*KN1 + kc*32 + quad*8);
            acc[t] = __builtin_amdgcn_mfma_f32_16x16x32_bf16(b, a1[kc], acc[t], 0, 0, 0);
        }
    }
    #pragma unroll
    for (int t = 0; t < 8; ++t) {
        int bc = (t*16 + quad*4) * 2;
        *(unsigned long long*)(Tb + l15*256 + (bc ^ rsw)) =
            pk4(silu_f(acc[t][0]), silu_f(acc[t][1]), silu_f(acc[t][2]), silu_f(acc[t][3]));
    }
    __builtin_amdgcn_wave_barrier();

    short8 a2[4];
    #pragma unroll
    for (int kc = 0; kc < 4; ++kc) {
        int bc = (kc*32 + quad*8) * 2;
        a2[kc] = *(const short8*)(Tb + l15*256 + (bc ^ rsw));
    }
    #pragma unroll
    for (int t = 0; t < 8; ++t) {
        float4 hv = *(const float4*)(h + (size_t)node*HID + t*16 + quad*4);
        float4 bb = *(const float4*)(b_n2 + t*16 + quad*4);
        acc[t] = (floatx4){hv.x + bb.x, hv.y + bb.y, hv.z + bb.z, hv.w + bb.w};
    }
    #pragma unroll
    for (int kc = 0; kc < 4; ++kc) {
        #pragma unroll
        for (int t = 0; t < 8; ++t) {
            short8 b = *(const short8*)(WT_n2 + (size_t)(t*16+l15)*HID + kc*32 + quad*8);
            acc[t] = __builtin_amdgcn_mfma_f32_16x16x32_bf16(b, a2[kc], acc[t], 0, 0, 0);
        }
    }
    #pragma unroll
    for (int t = 0; t < 8; ++t) {
        *(floatx4*)(h_out + (size_t)node*HID + t*16 + quad*4) = acc[t];
    }
}

extern "C" void kernel_launch(void* const* d_in, const int* in_sizes, int n_in,
                              void* d_out, int out_size, void* d_ws, size_t ws_size,
                              hipStream_t stream) {
    const float* h          = (const float*)d_in[0];
    const float* x          = (const float*)d_in[1];
    const float* edge_attr  = (const float*)d_in[2];
    const int*   edge_index = (const int*)  d_in[3];
    const int*   mask       = (const int*)  d_in[4];
    const float* W_e1 = (const float*)d_in[5];
    const float* b_e1 = (const float*)d_in[6];
    const float* W_e2 = (const float*)d_in[7];
    const float* b_e2 = (const float*)d_in[8];
    const float* W_g  = (const float*)d_in[9];
    const float* b_g  = (const float*)d_in[10];
    const float* W_n1 = (const float*)d_in[11];
    const float* b_n1 = (const float*)d_in[12];
    const float* W_n2 = (const float*)d_in[13];
    const float* b_n2 = (const float*)d_in[14];
    const float* W_x1 = (const float*)d_in[15];
    const float* b_x1 = (const float*)d_in[16];
    const float* W_x2 = (const float*)d_in[17];

    char* ws = (char*)d_ws;
    float* agg = (float*)ws;                       ws += (size_t)NN*HID*4;
    float* dxv = (float*)ws;                       ws += (size_t)NN*3*4;
    int*   counts = (int*)ws;                      ws += (size_t)NN*4;
    int*   cursor = (int*)ws;                      ws += (size_t)NN*4;
    uintx4* rec   = (uintx4*)ws;                   ws += (size_t)NE*32;
    unsigned short* PD    = (unsigned short*)ws;   ws += (size_t)NN*HID*2;
    unsigned short* PS    = (unsigned short*)ws;   ws += (size_t)NN*HID*2;
    unsigned short* WT1d  = (unsigned short*)ws;   ws += (size_t)HID*HID*2;
    unsigned short* WT1s  = (unsigned short*)ws;   ws += (size_t)HID*HID*2;
    unsigned short* WT1r  = (unsigned short*)ws;   ws += (size_t)HID*32*2;
    unsigned short* WT_e2 = (unsigned short*)ws;   ws += (size_t)HID*HID*2;
    unsigned short* WT_x1 = (unsigned short*)ws;   ws += (size_t)HID*HID*2;
    unsigned short* WT_n1 = (unsigned short*)ws;   ws += (size_t)HID*KN1*2;
    unsigned short* WT_n2 = (unsigned short*)ws;   ws += (size_t)HID*HID*2;

    hipMemsetAsync(counts, 0, (size_t)NN*sizeof(int), stream);

    // agg+dxv zeroing folded into prep grid: (NN*HID + NN*3)/4 = 655000 float4
    // -> ceil(655000/320) = 2048 zero blocks
    prep_hist_kernel<<<128 + NE/320 + 2048, 320, 0, stream>>>(
        W_e1, W_e2, W_x1, W_n1, W_n2,
        WT1d, WT1s, WT1r, WT_e2, WT_x1, WT_n1, WT_n2,
        edge_index, counts, (float4*)agg);

    scan_kernel<<<1, 1024, 0, stream>>>(counts, cursor);

    build_pd_kernel<<<PD_BLOCKS + NE/256, 256, 0, stream>>>(
        edge_index, x, edge_attr, cursor, rec,
        h, b_e1, WT1d, WT1s, PD, PS);

    egnn_edge_mfma<<<NE/64, 128, 0, stream>>>(
        rec, PD, PS, WT1r, WT_e2, WT_x1,
        b_e2, W_g, b_g, b_x1, W_x2, agg, dxv);

    float* h_out = (float*)d_out;
    float* x_out = h_out + (size_t)NN*HID;

    egnn_node_mfma<<<NN/16, 64, 0, stream>>>(
        h, x, mask, agg, dxv, WT_n1, b_n1, WT_n2, b_n2, h_out, x_out);
}